// Round 1
// baseline (383.625 us; speedup 1.0000x reference)
//
#include <hip/hip_runtime.h>

#define O_DIM   1024
#define C_DIM   512
#define HW      784
#define B_DIM   32
#define T_POS   8                // 8 consecutive n per wg => 32B-sector-clean HBM
#define NTILES  (HW / T_POS)     // 98
#define NTHREADS 512             // 8 waves: one wave per FFT row
#define RPAD    11               // odd pad -> conflict-free transpose writes

__device__ __forceinline__ float2 cmul(float2 a, float2 b) {
    return make_float2(a.x * b.x - a.y * b.y, a.x * b.y + a.y * b.x);
}

// Twiddle tables: C32[m] = cos(2*pi*m/32), S32[m] = sin(2*pi*m/32)
static constexpr float C32T[16] = {
    1.f, 0.98078528f, 0.92387953f, 0.83146961f,
    0.70710678f, 0.55557023f, 0.38268343f, 0.19509032f,
    0.f, -0.19509032f, -0.38268343f, -0.55557023f,
    -0.70710678f, -0.83146961f, -0.92387953f, -0.98078528f};
static constexpr float S32T[16] = {
    0.f, 0.19509032f, 0.38268343f, 0.55557023f,
    0.70710678f, 0.83146961f, 0.92387953f, 0.98078528f,
    1.f, 0.98078528f, 0.92387953f, 0.83146961f,
    0.70710678f, 0.55557023f, 0.38268343f, 0.19509032f};
static constexpr int REV4[16] = {0,8,4,12,2,10,6,14,1,9,5,13,3,11,7,15};

// Partner-half (lane ^ 32) value via v_permlane32_swap_b32 (VALU pipe, no LDS).
// XOR recovery r0^r1^own is exact and independent of which result slot holds
// which half's data.
__device__ __forceinline__ float other_half(float v) {
    unsigned u = __float_as_uint(v);
    auto r = __builtin_amdgcn_permlane32_swap(u, u, false, false);
    return __uint_as_float(((unsigned)r[0]) ^ ((unsigned)r[1]) ^ u);
}

// 32-point DIF FFT split across the two 32-lane halves of a wave.
// Lane (c, h) enters with y[j] = point n2 = 16*h + j of its column.
// Stage 0 (n2 <-> n2+16) crosses halves via permlane32_swap; stages 1..4 are a
// lane-local fft16. Exit: y[j] = X32[2*rev4(j) + h].  SGN=-1 fwd, +1 inv.
template<int SGN>
__device__ __forceinline__ void fft16x(float2 y[16], int h) {
    // ---- cross-half stage: lo lane has a=x[j], hi lane has b=x[j+16] ----
#pragma unroll
    for (int j = 0; j < 16; ++j) {
        float2 own = y[j];
        float2 oth = make_float2(other_half(own.x), other_half(own.y));
        float2 s = make_float2(own.x + oth.x, own.y + oth.y);  // a+b (both)
        float2 f = make_float2(own.x - oth.x, own.y - oth.y);  // lo: a-b, hi: b-a
        // hi needs (a-b)*W32^j = f * (-W32^j)  (sign folded into twiddle)
        float2 dd;
        if (j == 0) {
            dd = make_float2(-f.x, -f.y);
        } else if (j == 8) {
            dd = (SGN < 0) ? make_float2(-f.y, f.x) : make_float2(f.y, -f.x);
        } else {
            float2 wn = make_float2(-C32T[j], (SGN < 0) ? S32T[j] : -S32T[j]);
            dd = cmul(f, wn);
        }
        y[j] = h ? dd : s;
    }
    // ---- local 16-point DIF FFT (= stages 1..4 of the 32-pt FFT) ----
#pragma unroll
    for (int s = 0; s < 4; ++s) {
        const int hh = 8 >> s;
        const int L  = 16 >> s;
#pragma unroll
        for (int u = 0; u < 8; ++u) {
            const int blk = u >> (3 - s);
            const int t   = u & (hh - 1);
            const int i   = blk * L + t;
            const int m   = (t << s) * 2;      // twiddle W32^m == W16^(t<<s)
            float2 a = y[i], b = y[i + hh];
            y[i] = make_float2(a.x + b.x, a.y + b.y);
            float2 d = make_float2(a.x - b.x, a.y - b.y);
            if (m == 0) {
                y[i + hh] = d;
            } else if (m == 8) {
                y[i + hh] = (SGN < 0) ? make_float2(d.y, -d.x)
                                      : make_float2(-d.y, d.x);
            } else {
                float2 wv = make_float2(C32T[m], (SGN < 0) ? -S32T[m] : S32T[m]);
                y[i + hh] = cmul(d, wv);
            }
        }
    }
}

// Four-step 1024-pt FFT over zg[0..1023]; ONE full wave owns the row (16
// points per lane). Same-wave DS ordering -> wave barriers only.
// On return y[j] holds X[c + 32*(2*rev4(j)+h)]; caller does the epilogue.
template<int SGN>
__device__ __forceinline__ void wave_fft(float2* zg, int c, int h, float2 y[16]) {
#pragma unroll
    for (int j = 0; j < 16; ++j)                 // column c, n2 = 16h + j
        y[j] = zg[c + 32 * (16 * h + j)];
    __builtin_amdgcn_wave_barrier();
    fft16x<SGN>(y, h);                           // y[j] = A_c[2*rev4(j)+h]
    float sv, cv, sv2, cv2;
    __sincosf((float)SGN * 6.283185307179586f * (float)(c * h) * (1.f / 1024.f),
              &sv, &cv);                         // base: W1024^(c*h)
    __sincosf((float)SGN * 6.283185307179586f * (float)(2 * c) * (1.f / 1024.f),
              &sv2, &cv2);                       // step: W1024^(2c)
    float2 w = make_float2(cv, sv);
    const float2 stw = make_float2(cv2, sv2);
#pragma unroll
    for (int mm = 0; mm < 16; ++mm) {            // k2 = 2*mm + h, natural order
        float2 val = cmul(y[REV4[mm]], w);
        const int k2 = 2 * mm + h;
        zg[k2 * 32 + ((c + k2) & 31)] = val;     // row k2, swizzled col c
        w = cmul(w, stw);
    }
    __builtin_amdgcn_wave_barrier();
#pragma unroll
    for (int j = 0; j < 16; ++j)                 // row c, n1 = 16h + j
        y[j] = zg[c * 32 + ((16 * h + j + c) & 31)];
    __builtin_amdgcn_wave_barrier();
    fft16x<SGN>(y, h);                           // y[j] = X[c + 32*(2*rev4(j)+h)]
}

// One block per output row o; lanes sweep c coalesced. Each column c has
// exactly one nonzero across o, so the winning thread writes without races.
__global__ void extract_sketch(const float* __restrict__ sk1,
                               const float* __restrict__ sk2,
                               int* __restrict__ h, float* __restrict__ s) {
    const int o = blockIdx.x;                 // 0..1023
    for (int c = threadIdx.x; c < C_DIM; c += blockDim.x) {
        float v1 = sk1[o * C_DIM + c];
        if (v1 != 0.f) { h[c] = o; s[c] = v1; }
        float v2 = sk2[o * C_DIM + c];
        if (v2 != 0.f) { h[C_DIM + c] = o; s[C_DIM + c] = v2; }
    }
}

__global__ __launch_bounds__(NTHREADS, 4)
void cbp_main(const float* __restrict__ x1, const float* __restrict__ x2,
              const int* __restrict__ h1, const int* __restrict__ h2,
              const float* __restrict__ s1, const float* __restrict__ s2,
              float* __restrict__ out) {
    // 64 KB: Z = [8][1024] complex for scatter+FFT; after the FFTs die the
    // same space is reused as R = [1024][11] floats for the output transpose
    // (odd pad -> all 32 banks covered on the scalar transpose writes).
    __shared__ float4 LBUF[4096];
    float2 (*Z)[O_DIM] = reinterpret_cast<float2(*)[O_DIM]>(LBUF);
    float*  R = reinterpret_cast<float*>(LBUF);

    const int tid  = threadIdx.x;
    const int b    = blockIdx.x / NTILES;
    const int tile = blockIdx.x % NTILES;
    const int n0   = tile * T_POS;

    // ---- prefetch: one channel row per thread (512 threads = 512 channels) ----
    const int c = tid;
    const float* px1 = x1 + b * (C_DIM * HW) + c * HW + n0;
    const float* px2 = x2 + b * (C_DIM * HW) + c * HW + n0;
    float4 a0 = ((const float4*)px1)[0], a1 = ((const float4*)px1)[1];
    float4 d0 = ((const float4*)px2)[0], d1 = ((const float4*)px2)[1];
    const int   q1 = h1[c], q2 = h2[c];
    const float w1 = s1[c], w2 = s2[c];

    // ---- zero LDS (hides the global-load latency) ----
#pragma unroll
    for (int i = 0; i < 4096 / NTHREADS; ++i)
        LBUF[tid + NTHREADS * i] = make_float4(0.f, 0.f, 0.f, 0.f);
    __syncthreads();

    // ---- scatter: Z[pos][h1[c]].x += s1*x1, Z[pos][h2[c]].y += s2*x2 ----
    {
        float v[8] = {a0.x, a0.y, a0.z, a0.w, a1.x, a1.y, a1.z, a1.w};
#pragma unroll
        for (int j = 0; j < 8; ++j) atomicAdd(&Z[j][q1].x, w1 * v[j]);
        float u[8] = {d0.x, d0.y, d0.z, d0.w, d1.x, d1.y, d1.z, d1.w};
#pragma unroll
        for (int j = 0; j < 8; ++j) atomicAdd(&Z[j][q2].y, w2 * u[j]);
    }
    __syncthreads();

    const int wv   = tid >> 6;    // wave id = position row 0..7
    const int lane = tid & 63;
    const int cc   = lane & 31;   // column within the 32x32 four-step
    const int hh   = lane >> 5;   // half: n-range [16h, 16h+16)
    float2* zg = &Z[wv][0];
    float2 y[16];

    // ---- forward FFT of z = p1 + i*p2 (wave-local) ----
    wave_fft<-1>(zg, cc, hh, y);
#pragma unroll
    for (int mm = 0; mm < 16; ++mm)            // natural-order writeback
        zg[cc + 32 * (2 * mm + hh)] = y[REV4[mm]];
    __builtin_amdgcn_wave_barrier();

    // ---- Hermitian unpack + pointwise product (wave-local, 64 lanes) ----
#pragma unroll
    for (int m = 0; m < 8; ++m) {
        const int k = lane + (m << 6);
        if (k == 0) {
            float2 z0 = zg[0];
            float2 z5 = zg[512];
            zg[0]   = make_float2(z0.x * z0.y, 0.f);
            zg[512] = make_float2(z5.x * z5.y, 0.f);
        } else {
            float2 za = zg[k];
            float2 zb = zg[1024 - k];
            float2 F1 = make_float2(0.5f * (za.x + zb.x), 0.5f * (za.y - zb.y));
            float2 F2 = make_float2(0.5f * (za.y + zb.y), -0.5f * (za.x - zb.x));
            float2 G  = cmul(F1, F2);
            zg[k]        = G;
            zg[1024 - k] = make_float2(G.x, -G.y);
        }
    }
    __builtin_amdgcn_wave_barrier();

    // ---- inverse FFT; results stay in registers ----
    wave_fft<1>(zg, cc, hh, y);
    __syncthreads();              // all waves done with Z before R overlay

    // ---- stage transpose: R[o][wv] = conv[pos wv][bucket o] ----
#pragma unroll
    for (int mm = 0; mm < 16; ++mm)
        R[(cc + 32 * (2 * mm + hh)) * RPAD + wv] = y[REV4[mm]].x * (1.f / 1024.f);
    __syncthreads();

    // ---- store: 32 B (8 consecutive n) per o, sector-clean ----
    const int obase = b * (O_DIM * HW) + n0;
#pragma unroll
    for (int r = 0; r < O_DIM / NTHREADS; ++r) {
        const int o = tid + NTHREADS * r;
        const float* rp = &R[o * RPAD];
        float4 v0 = make_float4(rp[0], rp[1], rp[2], rp[3]);
        float4 v1 = make_float4(rp[4], rp[5], rp[6], rp[7]);
        float4* dst = (float4*)(out + obase + o * HW);
        dst[0] = v0;
        dst[1] = v1;
    }
}

extern "C" void kernel_launch(void* const* d_in, const int* in_sizes, int n_in,
                              void* d_out, int out_size, void* d_ws, size_t ws_size,
                              hipStream_t stream) {
    const float* x1  = (const float*)d_in[0];
    const float* x2  = (const float*)d_in[1];
    const float* sk1 = (const float*)d_in[2];
    const float* sk2 = (const float*)d_in[3];
    float* out = (float*)d_out;

    int*   h = (int*)d_ws;                         // [0..511]=h1, [512..1023]=h2
    float* s = (float*)((char*)d_ws + 4096);       // [0..511]=s1, [512..1023]=s2

    hipLaunchKernelGGL(extract_sketch, dim3(O_DIM), dim3(256), 0, stream,
                       sk1, sk2, h, s);
    hipLaunchKernelGGL(cbp_main, dim3(B_DIM * NTILES), dim3(NTHREADS), 0, stream,
                       x1, x2, h, h + C_DIM, s, s + C_DIM, out);
}

// Round 2
// 359.064 us; speedup vs baseline: 1.0684x; 1.0684x over previous
//
#include <hip/hip_runtime.h>

#define O_DIM   1024
#define C_DIM   512
#define HW      784
#define B_DIM   32
#define T_POS   8                // 8 consecutive n per wg => 32B-sector-clean HBM
#define NTILES  (HW / T_POS)     // 98
#define NTHREADS 256

__device__ __forceinline__ float2 cmul(float2 a, float2 b) {
    return make_float2(a.x * b.x - a.y * b.y, a.x * b.y + a.y * b.x);
}

static constexpr int REV5[32] = {
    0,16,8,24,4,20,12,28,2,18,10,26,6,22,14,30,
    1,17,9,25,5,21,13,29,3,19,11,27,7,23,15,31};

// 32-point in-register DIF FFT. SGN=-1 forward, +1 inverse (no scaling).
// Input natural order; output y[i] = X[rev5(i)].
template<int SGN>
__device__ __forceinline__ void fft32(float2 y[32]) {
    static constexpr float C32[16] = {
        1.f, 0.98078528f, 0.92387953f, 0.83146961f,
        0.70710678f, 0.55557023f, 0.38268343f, 0.19509032f,
        0.f, -0.19509032f, -0.38268343f, -0.55557023f,
        -0.70710678f, -0.83146961f, -0.92387953f, -0.98078528f};
    static constexpr float S32[16] = {
        0.f, 0.19509032f, 0.38268343f, 0.55557023f,
        0.70710678f, 0.83146961f, 0.92387953f, 0.98078528f,
        1.f, 0.98078528f, 0.92387953f, 0.83146961f,
        0.70710678f, 0.55557023f, 0.38268343f, 0.19509032f};
#pragma unroll
    for (int s = 0; s < 5; ++s) {
        const int L = 32 >> s;
        const int h = 16 >> s;
#pragma unroll
        for (int u = 0; u < 16; ++u) {
            const int blk = u >> (4 - s);
            const int t   = u & (h - 1);
            const int i   = blk * L + t;
            const int m   = t << s;            // twiddle index: W32^m
            float2 a = y[i], b = y[i + h];
            y[i] = make_float2(a.x + b.x, a.y + b.y);
            float2 d = make_float2(a.x - b.x, a.y - b.y);
            if (m == 0) {
                y[i + h] = d;
            } else if (m == 8) {
                y[i + h] = (SGN < 0) ? make_float2(d.y, -d.x)
                                     : make_float2(-d.y, d.x);
            } else {
                float2 w = make_float2(C32[m], (SGN < 0) ? -S32[m] : S32[m]);
                y[i + h] = cmul(d, w);
            }
        }
    }
}

// Second half of the four-step: y[rev5(k2)] = A[p][k2] on entry.
// Twiddle by W1024^(SGN*p*k2) (4 independent chains, depth ~12 instead of 31),
// scatter to swizzled rows, same-wave transpose read, final fft32.
// On return y[rev5(k1)] = X[p + 32*k1].
template<int SGN>
__device__ __forceinline__ void four_step_B(float2* zg, int p, float2 y[32]) {
    float sv, cv;
    __sincosf((float)SGN * 6.283185307179586f * (float)p * (1.f / 1024.f), &sv, &cv);
    const float2 stw = make_float2(cv, sv);      // W1024^(SGN*p)
    float2 t2  = cmul(stw, stw);
    float2 t4  = cmul(t2, t2);
    float2 s8  = cmul(t4, t4);                   // stw^8
    float2 s16 = cmul(s8, s8);                   // stw^16
    float2 s24 = cmul(s16, s8);                  // stw^24
    float2 wq0 = make_float2(1.f, 0.f), wq1 = s8, wq2 = s16, wq3 = s24;
#pragma unroll
    for (int m = 0; m < 8; ++m) {
        {   const int k2 = m;                     // chain 0
            float2 val = y[REV5[k2]];
            if (k2 > 0) val = cmul(val, wq0);
            zg[k2 * 32 + ((p + k2) & 31)] = val; }
        {   const int k2 = 8 + m;                 // chain 1
            float2 val = cmul(y[REV5[k2]], wq1);
            zg[k2 * 32 + ((p + k2) & 31)] = val; }
        {   const int k2 = 16 + m;                // chain 2
            float2 val = cmul(y[REV5[k2]], wq2);
            zg[k2 * 32 + ((p + k2) & 31)] = val; }
        {   const int k2 = 24 + m;                // chain 3
            float2 val = cmul(y[REV5[k2]], wq3);
            zg[k2 * 32 + ((p + k2) & 31)] = val; }
        if (m < 7) {
            wq0 = cmul(wq0, stw); wq1 = cmul(wq1, stw);
            wq2 = cmul(wq2, stw); wq3 = cmul(wq3, stw);
        }
    }
    __builtin_amdgcn_wave_barrier();
#pragma unroll
    for (int n1 = 0; n1 < 32; ++n1)
        y[n1] = zg[p * 32 + ((n1 + p) & 31)];
    __builtin_amdgcn_wave_barrier();
    fft32<SGN>(y);
}

// One block per output row o; lanes sweep c coalesced. Each column c has
// exactly one nonzero across o, so the winning thread writes without races.
__global__ void extract_sketch(const float* __restrict__ sk1,
                               const float* __restrict__ sk2,
                               int* __restrict__ h, float* __restrict__ s) {
    const int o = blockIdx.x;                 // 0..1023
    for (int c = threadIdx.x; c < C_DIM; c += blockDim.x) {
        float v1 = sk1[o * C_DIM + c];
        if (v1 != 0.f) { h[c] = o; s[c] = v1; }
        float v2 = sk2[o * C_DIM + c];
        if (v2 != 0.f) { h[C_DIM + c] = o; s[C_DIM + c] = v2; }
    }
}

__global__ __launch_bounds__(NTHREADS, 2)
void cbp_main(const float* __restrict__ x1, const float* __restrict__ x2,
              const int* __restrict__ h1, const int* __restrict__ h2,
              const float* __restrict__ s1, const float* __restrict__ s2,
              float* __restrict__ out) {
    // 64 KB: Z = [8][1024] complex for scatter+FFT; after the FFTs die,
    // the same space is reused as R = [1024][10] floats (pad 10 -> 2-way
    // bank aliasing only, 8B-aligned rows) for the output transpose.
    __shared__ float4 LBUF[4096];
    float2 (*Z)[O_DIM] = reinterpret_cast<float2(*)[O_DIM]>(LBUF);
    float*  R = reinterpret_cast<float*>(LBUF);

    const int tid  = threadIdx.x;
    const int b    = blockIdx.x / NTILES;
    const int tile = blockIdx.x % NTILES;
    const int n0   = tile * T_POS;

    // ---- prefetch x-tile (two channel rows per thread, 32 B each) ----
    const int c0 = tid;
    const int c1 = tid + NTHREADS;
    const int xoff = b * (C_DIM * HW) + n0;
    const float4* p10 = (const float4*)(x1 + xoff + c0 * HW);
    const float4* p11 = (const float4*)(x1 + xoff + c1 * HW);
    const float4* p20 = (const float4*)(x2 + xoff + c0 * HW);
    const float4* p21 = (const float4*)(x2 + xoff + c1 * HW);
    float4 a0 = p10[0], a1 = p10[1];   // x1 row c0, n0..n0+7
    float4 b0 = p11[0], b1 = p11[1];   // x1 row c1
    float4 d0 = p20[0], d1 = p20[1];   // x2 row c0
    float4 e0 = p21[0], e1 = p21[1];   // x2 row c1
    const int   q10 = h1[c0], q11 = h1[c1], q20 = h2[c0], q21 = h2[c1];
    const float w10 = s1[c0], w11 = s1[c1], w20 = s2[c0], w21 = s2[c1];

    // ---- zero LDS (hides the global-load latency) ----
#pragma unroll
    for (int i = 0; i < 4096 / NTHREADS; ++i)
        LBUF[tid + NTHREADS * i] = make_float4(0.f, 0.f, 0.f, 0.f);
    __syncthreads();

    // ---- scatter: Z[pos][h1[c]].x += s1*x1, Z[pos][h2[c]].y += s2*x2 ----
    {
        float v[8];
        v[0]=a0.x; v[1]=a0.y; v[2]=a0.z; v[3]=a0.w;
        v[4]=a1.x; v[5]=a1.y; v[6]=a1.z; v[7]=a1.w;
#pragma unroll
        for (int j = 0; j < 8; ++j) atomicAdd(&Z[j][q10].x, w10 * v[j]);
        v[0]=b0.x; v[1]=b0.y; v[2]=b0.z; v[3]=b0.w;
        v[4]=b1.x; v[5]=b1.y; v[6]=b1.z; v[7]=b1.w;
#pragma unroll
        for (int j = 0; j < 8; ++j) atomicAdd(&Z[j][q11].x, w11 * v[j]);
        v[0]=d0.x; v[1]=d0.y; v[2]=d0.z; v[3]=d0.w;
        v[4]=d1.x; v[5]=d1.y; v[6]=d1.z; v[7]=d1.w;
#pragma unroll
        for (int j = 0; j < 8; ++j) atomicAdd(&Z[j][q20].y, w20 * v[j]);
        v[0]=e0.x; v[1]=e0.y; v[2]=e0.z; v[3]=e0.w;
        v[4]=e1.x; v[5]=e1.y; v[6]=e1.z; v[7]=e1.w;
#pragma unroll
        for (int j = 0; j < 8; ++j) atomicAdd(&Z[j][q21].y, w21 * v[j]);
    }
    __syncthreads();

    const int g    = tid >> 5;       // position group 0..7 (half-wave)
    const int p    = tid & 31;
    const int lane = tid & 63;
    float2* zg = &Z[g][0];
    float2 y[32];

    // ---- forward FFT of z = p1 + i*p2 (wave-local) ----
#pragma unroll
    for (int n2 = 0; n2 < 32; ++n2)
        y[n2] = zg[p + 32 * n2];
    __builtin_amdgcn_wave_barrier();
    fft32<-1>(y);
    four_step_B<-1>(zg, p, y);
    // now y[rev5(k1)] = X[p + 32*k1]  (lane p holds spectral column p)

    // ---- Hermitian unpack + pointwise product, fully in registers ----
    // G[k] for k = p+32*n2 needs zb = X[1024-k], which lives at lane
    // (32-p)&31, index 31-n2 (p>=1). Fixed half-wave pairing -> ds_bpermute.
    // Lane 0 self-patches from its own registers (index (32-n2)&31).
    // k=0 and k=512 (za==zb) fall out of the general formula automatically.
    const int paddr = (((lane & 32) | ((32 - p) & 31))) << 2;
    float2 gg[32];
#pragma unroll
    for (int n2 = 0; n2 < 32; ++n2) {
        float2 za = y[REV5[n2]];
        float2 yb = y[REV5[31 - n2]];
        float2 zb;
        zb.x = __uint_as_float((unsigned)__builtin_amdgcn_ds_bpermute(
                   paddr, (int)__float_as_uint(yb.x)));
        zb.y = __uint_as_float((unsigned)__builtin_amdgcn_ds_bpermute(
                   paddr, (int)__float_as_uint(yb.y)));
        float2 self = y[REV5[(32 - n2) & 31]];
        zb.x = (p == 0) ? self.x : zb.x;
        zb.y = (p == 0) ? self.y : zb.y;
        float2 F1 = make_float2(0.5f * (za.x + zb.x), 0.5f * (za.y - zb.y));
        float2 F2 = make_float2(0.5f * (za.y + zb.y), -0.5f * (za.x - zb.x));
        gg[n2] = cmul(F1, F2);     // G[p + 32*n2], natural order in n2
    }

    // ---- inverse FFT directly on registers (step-A LDS read eliminated) ----
    fft32<1>(gg);
    four_step_B<1>(zg, p, gg);
    __syncthreads();              // all groups done with Z before R overlay

    // ---- stage transpose: R[o][g] = conv[pos g][bucket o] ----
#pragma unroll
    for (int k1 = 0; k1 < 32; ++k1)
        R[(p + 32 * k1) * 10 + g] = gg[REV5[k1]].x * (1.f / 1024.f);
    __syncthreads();

    // ---- store: 32 B (8 consecutive n) per o, sector-clean ----
    const int obase = b * (O_DIM * HW) + n0;
#pragma unroll
    for (int r = 0; r < O_DIM / NTHREADS; ++r) {
        const int o = tid + NTHREADS * r;
        const float* rp = &R[o * 10];
        float4 v0 = make_float4(rp[0], rp[1], rp[2], rp[3]);
        float4 v1 = make_float4(rp[4], rp[5], rp[6], rp[7]);
        float4* dst = (float4*)(out + obase + o * HW);
        dst[0] = v0;
        dst[1] = v1;
    }
}

extern "C" void kernel_launch(void* const* d_in, const int* in_sizes, int n_in,
                              void* d_out, int out_size, void* d_ws, size_t ws_size,
                              hipStream_t stream) {
    const float* x1  = (const float*)d_in[0];
    const float* x2  = (const float*)d_in[1];
    const float* sk1 = (const float*)d_in[2];
    const float* sk2 = (const float*)d_in[3];
    float* out = (float*)d_out;

    int*   h = (int*)d_ws;                         // [0..511]=h1, [512..1023]=h2
    float* s = (float*)((char*)d_ws + 4096);       // [0..511]=s1, [512..1023]=s2

    hipLaunchKernelGGL(extract_sketch, dim3(O_DIM), dim3(256), 0, stream,
                       sk1, sk2, h, s);
    hipLaunchKernelGGL(cbp_main, dim3(B_DIM * NTILES), dim3(NTHREADS), 0, stream,
                       x1, x2, h, h + C_DIM, s, s + C_DIM, out);
}